// Round 4
// baseline (1216.413 us; speedup 1.0000x reference)
//
#include <hip/hip_runtime.h>
#include <math.h>

// Problem constants (fixed by setup_inputs)
constexpr int B_ = 8;
constexpr int N_ = 2048;
constexpr int D_ = 256;
constexpr int H_ = 16;
constexpr int K_ = 8;
constexpr int CAND = 32;   // candidate pool for exact re-ranking

typedef __bf16 bf16x8 __attribute__((ext_vector_type(8)));
typedef float  f32x4  __attribute__((ext_vector_type(4)));

// ---------------------------------------------------------------------------
// Kernel 1: fp32 inverse norms for f1/f2 rows (GEMM staging only)
// ---------------------------------------------------------------------------
__global__ __launch_bounds__(256)
void norm_kernel(const float* __restrict__ f1, const float* __restrict__ f2,
                 float* __restrict__ inv1, float* __restrict__ inv2) {
    int gid  = blockIdx.x * blockDim.x + threadIdx.x;
    int wave = gid >> 6;
    int lane = gid & 63;
    if (wave >= 2 * B_ * N_) return;
    bool is1 = wave < B_ * N_;
    int row = is1 ? wave : wave - B_ * N_;
    const float* r = (is1 ? f1 : f2) + (size_t)row * D_;
    float ss = 0.f;
#pragma unroll
    for (int j = 0; j < D_ / 64; j++) {
        float v = r[lane + 64 * j];
        ss += v * v;
    }
#pragma unroll
    for (int off = 32; off > 0; off >>= 1) ss += __shfl_xor(ss, off, 64);
    if (lane == 0) (is1 ? inv1 : inv2)[row] = 1.0f / (sqrtf(ss) + 1e-8f);
}

// ---------------------------------------------------------------------------
// split fp32*scale -> packed bf16 hi (truncated) + bf16 lo (residual, trunc)
// ---------------------------------------------------------------------------
__device__ inline void split4(float4 v, float s, uint2& hi, uint2& lo) {
    float a = v.x * s, b = v.y * s, c = v.z * s, d = v.w * s;
    unsigned ua = __float_as_uint(a), ub = __float_as_uint(b);
    unsigned uc = __float_as_uint(c), ud = __float_as_uint(d);
    unsigned ha = ua & 0xFFFF0000u, hb = ub & 0xFFFF0000u;
    unsigned hc = uc & 0xFFFF0000u, hd = ud & 0xFFFF0000u;
    hi.x = (ha >> 16) | hb;
    hi.y = (hc >> 16) | hd;
    float ra = a - __uint_as_float(ha), rb = b - __uint_as_float(hb);
    float rc = c - __uint_as_float(hc), rd = d - __uint_as_float(hd);
    lo.x = (__float_as_uint(ra) >> 16) | (__float_as_uint(rb) & 0xFFFF0000u);
    lo.y = (__float_as_uint(rc) >> 16) | (__float_as_uint(rd) & 0xFFFF0000u);
}

// ---------------------------------------------------------------------------
// Kernel 2: MFMA cosine-sim GEMM (bf16x3 split precision) + coord dist + MLP
// Verified correct in rounds 2/3 (f-output passes); ~1e-4 error on w is
// handled by the 32-candidate exact re-ranking in the topk kernel.
// ---------------------------------------------------------------------------
constexpr int BM = 128;   // q rows per block
constexpr int BK = 32;    // k chunk (one mfma K)
constexpr int LDA = 40;   // padded row stride in bf16 (80 B, 16B-aligned)

__global__ __launch_bounds__(256, 2)
void gemm_mlp_kernel(const float* __restrict__ f1, const float* __restrict__ f2,
                     const float* __restrict__ pc, const float* __restrict__ qc,
                     const float* __restrict__ inv1, const float* __restrict__ inv2,
                     const float* __restrict__ pW1, const float* __restrict__ pb1,
                     const float* __restrict__ pW2, const float* __restrict__ pb2,
                     float* __restrict__ w_out) {
    __shared__ unsigned short Ahi[BM][LDA];
    __shared__ unsigned short Alo[BM][LDA];
    __shared__ unsigned short Bhi[BM][LDA];
    __shared__ unsigned short Blo[BM][LDA];

    int tid = threadIdx.x;
    int pBase = blockIdx.x * BM;
    int qBase = blockIdx.y * BM;
    int b = blockIdx.z;

    int srow = tid >> 1;
    int shalf = tid & 1;
    float ia = inv2[b * N_ + qBase + srow];
    float ib = inv1[b * N_ + pBase + srow];
    const float* Abase = f2 + ((size_t)(b * N_ + qBase) + srow) * D_ + shalf * 16;
    const float* Bbase = f1 + ((size_t)(b * N_ + pBase) + srow) * D_ + shalf * 16;

    int lane = tid & 63;
    int wv = tid >> 6;
    int wq = (wv >> 1) * 64;
    int wp = (wv & 1) * 64;
    int fr = lane & 15;
    int kg = lane >> 4;

    f32x4 acc[4][4] = {};

    for (int kb = 0; kb < D_; kb += BK) {
        __syncthreads();
        float4 a0 = *(const float4*)(Abase + kb + 0);
        float4 a1 = *(const float4*)(Abase + kb + 4);
        float4 a2 = *(const float4*)(Abase + kb + 8);
        float4 a3 = *(const float4*)(Abase + kb + 12);
        float4 b0 = *(const float4*)(Bbase + kb + 0);
        float4 b1 = *(const float4*)(Bbase + kb + 4);
        float4 b2 = *(const float4*)(Bbase + kb + 8);
        float4 b3 = *(const float4*)(Bbase + kb + 12);
        uint2 h0, l0, h1, l1, h2, l2, h3, l3;
        split4(a0, ia, h0, l0); split4(a1, ia, h1, l1);
        split4(a2, ia, h2, l2); split4(a3, ia, h3, l3);
        *(uint4*)&Ahi[srow][shalf * 16]     = uint4{h0.x, h0.y, h1.x, h1.y};
        *(uint4*)&Ahi[srow][shalf * 16 + 8] = uint4{h2.x, h2.y, h3.x, h3.y};
        *(uint4*)&Alo[srow][shalf * 16]     = uint4{l0.x, l0.y, l1.x, l1.y};
        *(uint4*)&Alo[srow][shalf * 16 + 8] = uint4{l2.x, l2.y, l3.x, l3.y};
        split4(b0, ib, h0, l0); split4(b1, ib, h1, l1);
        split4(b2, ib, h2, l2); split4(b3, ib, h3, l3);
        *(uint4*)&Bhi[srow][shalf * 16]     = uint4{h0.x, h0.y, h1.x, h1.y};
        *(uint4*)&Bhi[srow][shalf * 16 + 8] = uint4{h2.x, h2.y, h3.x, h3.y};
        *(uint4*)&Blo[srow][shalf * 16]     = uint4{l0.x, l0.y, l1.x, l1.y};
        *(uint4*)&Blo[srow][shalf * 16 + 8] = uint4{l2.x, l2.y, l3.x, l3.y};
        __syncthreads();

        bf16x8 ah[4], al[4], bh[4], bl[4];
#pragma unroll
        for (int t = 0; t < 4; t++) {
            ah[t] = *(const bf16x8*)&Ahi[wq + t * 16 + fr][kg * 8];
            al[t] = *(const bf16x8*)&Alo[wq + t * 16 + fr][kg * 8];
            bh[t] = *(const bf16x8*)&Bhi[wp + t * 16 + fr][kg * 8];
            bl[t] = *(const bf16x8*)&Blo[wp + t * 16 + fr][kg * 8];
        }
#pragma unroll
        for (int qt = 0; qt < 4; qt++) {
#pragma unroll
            for (int pt = 0; pt < 4; pt++) {
                acc[qt][pt] = __builtin_amdgcn_mfma_f32_16x16x32_bf16(
                    ah[qt], bh[pt], acc[qt][pt], 0, 0, 0);
                acc[qt][pt] = __builtin_amdgcn_mfma_f32_16x16x32_bf16(
                    ah[qt], bl[pt], acc[qt][pt], 0, 0, 0);
                acc[qt][pt] = __builtin_amdgcn_mfma_f32_16x16x32_bf16(
                    al[qt], bh[pt], acc[qt][pt], 0, 0, 0);
            }
        }
    }

    // ---------------- epilogue: coord term + MLP + store -------------------
    float px[4], py[4], pz[4], pn2[4];
    int pg[4];
#pragma unroll
    for (int pt = 0; pt < 4; pt++) {
        int p = pBase + wp + pt * 16 + fr;
        pg[pt] = p;
        const float* pp = pc + ((size_t)(b * N_ + p)) * 3;
        px[pt] = pp[0]; py[pt] = pp[1]; pz[pt] = pp[2];
        pn2[pt] = px[pt] * px[pt] + py[pt] * py[pt] + pz[pt] * pz[pt];
    }
#pragma unroll
    for (int qt = 0; qt < 4; qt++) {
        float qx[4], qy[4], qz[4], qq2[4];
        int q0 = qBase + wq + qt * 16 + kg * 4;
#pragma unroll
        for (int r = 0; r < 4; r++) {
            const float* qp = qc + ((size_t)(b * N_ + q0 + r)) * 3;
            qx[r] = qp[0]; qy[r] = qp[1]; qz[r] = qp[2];
            qq2[r] = qx[r] * qx[r] + qy[r] * qy[r] + qz[r] * qz[r];
        }
#pragma unroll
        for (int pt = 0; pt < 4; pt++) {
            f32x4 c = acc[qt][pt];
#pragma unroll
            for (int r = 0; r < 4; r++) {
                float w1v = c[r];
                float d2 = qq2[r] + pn2[pt]
                         - 2.f * (qx[r] * px[pt] + qy[r] * py[pt] + qz[r] * pz[pt]);
                float w2v = -fmaxf(d2, 0.f);
                float out = pb2[0];
#pragma unroll
                for (int h = 0; h < H_; h++) {
                    float t = pW1[2 * h] * w1v + pW1[2 * h + 1] * w2v + pb1[h];
                    out += pW2[h] * fmaxf(t, 0.f);
                }
                w_out[((size_t)(b * N_ + q0 + r)) * N_ + pg[pt]] = out;
            }
        }
    }
}

// ---------------------------------------------------------------------------
// Kernel 3: approx top-32 candidates -> exact fp64 rescore -> exact top-8
// + softmax + gather + pool. One wave per (b,q) row.
// ---------------------------------------------------------------------------
__global__ __launch_bounds__(256)
void topk_kernel(const float* __restrict__ w, const float* __restrict__ f1,
                 const float* __restrict__ f2,
                 const float* __restrict__ pc, const float* __restrict__ qc,
                 const float* __restrict__ pW1, const float* __restrict__ pb1,
                 const float* __restrict__ pW2, const float* __restrict__ pb2,
                 float* __restrict__ f_out, float* __restrict__ idx_out) {
    int gid  = blockIdx.x * blockDim.x + threadIdx.x;
    int row  = gid >> 6;
    int lane = gid & 63;
    if (row >= B_ * N_) return;
    int b = row >> 11;
    const float* wrow = w + (size_t)row * N_;

    // ---- phase 1: per-lane sorted top-8 scan of approx scores ----
    float tv[K_];
    int   ti[K_];
#pragma unroll
    for (int s = 0; s < K_; s++) { tv[s] = -INFINITY; ti[s] = 0x7fffffff; }
    for (int j = 0; j < N_ / 256; j++) {
        float4 v4 = *(const float4*)(wrow + lane * 4 + j * 256);
        float vv[4] = {v4.x, v4.y, v4.z, v4.w};
#pragma unroll
        for (int c = 0; c < 4; c++) {
            float v = vv[c];
            if (v > tv[K_ - 1]) {
                int idx = lane * 4 + j * 256 + c;
                tv[K_ - 1] = v; ti[K_ - 1] = idx;
#pragma unroll
                for (int s = K_ - 1; s > 0; s--) {
                    if (tv[s] > tv[s - 1]) {
                        float tf = tv[s]; tv[s] = tv[s - 1]; tv[s - 1] = tf;
                        int tn = ti[s]; ti[s] = ti[s - 1]; ti[s - 1] = tn;
                    }
                }
            }
        }
    }

    // ---- phase 2: pop 32 wave-wide candidates (approx order) ----
    int cand[CAND];
#pragma unroll
    for (int r = 0; r < CAND; r++) {
        float bv = tv[0];
        int   bi = ti[0];
#pragma unroll
        for (int off = 1; off < 64; off <<= 1) {
            float ov = __shfl_xor(bv, off, 64);
            int   oi = __shfl_xor(bi, off, 64);
            if (ov > bv || (ov == bv && oi < bi)) { bv = ov; bi = oi; }
        }
        cand[r] = bi;
        if (ti[0] == bi) {
#pragma unroll
            for (int s = 0; s < K_ - 1; s++) { tv[s] = tv[s + 1]; ti[s] = ti[s + 1]; }
            tv[K_ - 1] = -INFINITY; ti[K_ - 1] = 0x7fffffff;
        }
    }

    // ---- phase 3: exact fp64 rescore of the 32 candidates ----
    const float* f2r = f2 + (size_t)row * D_;
    double aqd[4];
    double daa = 0.0;
#pragma unroll
    for (int t = 0; t < 4; t++) {
        aqd[t] = (double)f2r[lane + 64 * t];
        daa += aqd[t] * aqd[t];
    }
#pragma unroll
    for (int off = 1; off < 64; off <<= 1) daa += __shfl_xor(daa, off, 64);
    double inv_a = 1.0 / (sqrt(daa) + 1e-8);

    double mydab = 0.0, mydbb = 0.0;  // lane j (<32) holds cand[j]'s sums
#pragma unroll
    for (int j = 0; j < CAND; j++) {
        int cj = cand[j];
        const float* f1r = f1 + ((size_t)(b * N_ + cj)) * D_;
        double sab = 0.0, sbb = 0.0;
#pragma unroll
        for (int t = 0; t < 4; t++) {
            double bvd = (double)f1r[lane + 64 * t];
            sab += aqd[t] * bvd;
            sbb += bvd * bvd;
        }
#pragma unroll
        for (int off = 1; off < 64; off <<= 1) {
            sab += __shfl_xor(sab, off, 64);
            sbb += __shfl_xor(sbb, off, 64);
        }
        if (lane == j) { mydab = sab; mydbb = sbb; }
    }

    double ex = -INFINITY;
    int    ei = 0x7fffffff;
    if (lane < CAND) {
        int ci = 0;
#pragma unroll
        for (int j = 0; j < CAND; j++) if (lane == j) ci = cand[j];
        ei = ci;
        double w1d = mydab * inv_a * (1.0 / (sqrt(mydbb) + 1e-8));
        const float* qp = qc + (size_t)row * 3;
        double qx = qp[0], qy = qp[1], qz = qp[2];
        const float* pp = pc + ((size_t)(b * N_ + ci)) * 3;
        double px = pp[0], py = pp[1], pz = pp[2];
        double d2 = (qx * qx + qy * qy + qz * qz) + (px * px + py * py + pz * pz)
                  - 2.0 * (qx * px + qy * py + qz * pz);
        double w2d = -fmax(d2, 0.0);
        double out = (double)pb2[0];
#pragma unroll
        for (int h = 0; h < H_; h++) {
            double t = (double)pW1[2 * h] * w1d + (double)pW1[2 * h + 1] * w2d
                     + (double)pb1[h];
            out += (double)pW2[h] * fmax(t, 0.0);
        }
        ex = out;
    }

    // ---- phase 4: exact top-8 over 32 lanes (desc, smaller idx on tie) ----
    double outv[K_];
    int    outi[K_];
#pragma unroll
    for (int r = 0; r < K_; r++) {
        double bv = ex;
        int    bi = ei;
#pragma unroll
        for (int off = 1; off < 64; off <<= 1) {
            double ov = __shfl_xor(bv, off, 64);
            int    oi = __shfl_xor(bi, off, 64);
            if (ov > bv || (ov == bv && oi < bi)) { bv = ov; bi = oi; }
        }
        outv[r] = bv; outi[r] = bi;
        if (ei == bi) ex = -INFINITY;   // owning lane retires its candidate
    }

    // ---- phase 5: softmax + gather + pool + write ----
    float m = (float)outv[0];
    float e[K_], s = 0.f;
#pragma unroll
    for (int r = 0; r < K_; r++) { e[r] = expf((float)outv[r] - m); s += e[r]; }
    float inv_s = 1.f / s;

    const float* f1b = f1 + ((size_t)b * N_) * D_;
    size_t obase = (size_t)row * (2 * D_);
#pragma unroll
    for (int jd = 0; jd < D_ / 64; jd++) {
        int d = lane + 64 * jd;
        float accv = 0.f, mx = -INFINITY;
#pragma unroll
        for (int r = 0; r < K_; r++) {
            float x = f1b[(size_t)outi[r] * D_ + d];
            accv += (e[r] * inv_s) * x;
            mx = fmaxf(mx, x);
        }
        f_out[obase + d]      = accv;
        f_out[obase + D_ + d] = mx;
    }
    if (lane == 0) {
#pragma unroll
        for (int r = 0; r < K_; r++) idx_out[(size_t)row * K_ + r] = (float)outi[r];
    }
}

// ---------------------------------------------------------------------------
extern "C" void kernel_launch(void* const* d_in, const int* in_sizes, int n_in,
                              void* d_out, int out_size, void* d_ws, size_t ws_size,
                              hipStream_t stream) {
    const float* f1 = (const float*)d_in[0];
    const float* f2 = (const float*)d_in[1];
    const float* pc = (const float*)d_in[2];
    const float* qc = (const float*)d_in[3];
    const float* W1 = (const float*)d_in[4];
    const float* b1 = (const float*)d_in[5];
    const float* W2 = (const float*)d_in[6];
    const float* b2 = (const float*)d_in[7];

    float* out     = (float*)d_out;
    float* f_out   = out;                                   // [B,N,2D]
    float* idx_out = f_out + (size_t)B_ * N_ * 2 * D_;      // [B,N,K] as float
    float* w_out   = idx_out + (size_t)B_ * N_ * K_;        // [B,N,N]

    float* inv1 = (float*)d_ws;        // [B*N]
    float* inv2 = inv1 + B_ * N_;      // [B*N]

    norm_kernel<<<(2 * B_ * N_) / 4, 256, 0, stream>>>(f1, f2, inv1, inv2);

    dim3 g2(N_ / BM, N_ / BM, B_);
    gemm_mlp_kernel<<<g2, 256, 0, stream>>>(f1, f2, pc, qc, inv1, inv2,
                                            W1, b1, W2, b2, w_out);

    topk_kernel<<<(B_ * N_) / 4, 256, 0, stream>>>(w_out, f1, f2, pc, qc,
                                                   W1, b1, W2, b2,
                                                   f_out, idx_out);
}

// Round 5
// 742.033 us; speedup vs baseline: 1.6393x; 1.6393x over previous
//
#include <hip/hip_runtime.h>
#include <math.h>

// Problem constants (fixed by setup_inputs)
constexpr int B_ = 8;
constexpr int N_ = 2048;
constexpr int D_ = 256;
constexpr int H_ = 16;
constexpr int K_ = 8;
constexpr int CAND = 32;   // candidate pool for exact re-ranking

typedef __bf16 bf16x8 __attribute__((ext_vector_type(8)));
typedef float  f32x4  __attribute__((ext_vector_type(4)));

// ---------------------------------------------------------------------------
// Kernel 1: fp32 inverse norms for f1/f2 rows (GEMM staging only)
// ---------------------------------------------------------------------------
__global__ __launch_bounds__(256)
void norm_kernel(const float* __restrict__ f1, const float* __restrict__ f2,
                 float* __restrict__ inv1, float* __restrict__ inv2) {
    int gid  = blockIdx.x * blockDim.x + threadIdx.x;
    int wave = gid >> 6;
    int lane = gid & 63;
    if (wave >= 2 * B_ * N_) return;
    bool is1 = wave < B_ * N_;
    int row = is1 ? wave : wave - B_ * N_;
    const float* r = (is1 ? f1 : f2) + (size_t)row * D_;
    float ss = 0.f;
#pragma unroll
    for (int j = 0; j < D_ / 64; j++) {
        float v = r[lane + 64 * j];
        ss += v * v;
    }
#pragma unroll
    for (int off = 32; off > 0; off >>= 1) ss += __shfl_xor(ss, off, 64);
    if (lane == 0) (is1 ? inv1 : inv2)[row] = 1.0f / (sqrtf(ss) + 1e-8f);
}

// ---------------------------------------------------------------------------
// split fp32*scale -> packed bf16 hi (truncated) + bf16 lo (residual, trunc)
// ---------------------------------------------------------------------------
__device__ inline void split4(float4 v, float s, uint2& hi, uint2& lo) {
    float a = v.x * s, b = v.y * s, c = v.z * s, d = v.w * s;
    unsigned ua = __float_as_uint(a), ub = __float_as_uint(b);
    unsigned uc = __float_as_uint(c), ud = __float_as_uint(d);
    unsigned ha = ua & 0xFFFF0000u, hb = ub & 0xFFFF0000u;
    unsigned hc = uc & 0xFFFF0000u, hd = ud & 0xFFFF0000u;
    hi.x = (ha >> 16) | hb;
    hi.y = (hc >> 16) | hd;
    float ra = a - __uint_as_float(ha), rb = b - __uint_as_float(hb);
    float rc = c - __uint_as_float(hc), rd = d - __uint_as_float(hd);
    lo.x = (__float_as_uint(ra) >> 16) | (__float_as_uint(rb) & 0xFFFF0000u);
    lo.y = (__float_as_uint(rc) >> 16) | (__float_as_uint(rd) & 0xFFFF0000u);
}

// ---------------------------------------------------------------------------
// Kernel 2: MFMA cosine-sim GEMM (bf16x3 split precision) + coord dist + MLP
// Verified correct rounds 2-4 (f passes); ~1e-4 error on w handled by the
// 32-candidate exact re-ranking in the topk kernel.
// ---------------------------------------------------------------------------
constexpr int BM = 128;   // q rows per block
constexpr int BK = 32;    // k chunk (one mfma K)
constexpr int LDA = 40;   // padded row stride in bf16 (80 B, 16B-aligned)

__global__ __launch_bounds__(256, 2)
void gemm_mlp_kernel(const float* __restrict__ f1, const float* __restrict__ f2,
                     const float* __restrict__ pc, const float* __restrict__ qc,
                     const float* __restrict__ inv1, const float* __restrict__ inv2,
                     const float* __restrict__ pW1, const float* __restrict__ pb1,
                     const float* __restrict__ pW2, const float* __restrict__ pb2,
                     float* __restrict__ w_out) {
    __shared__ unsigned short Ahi[BM][LDA];
    __shared__ unsigned short Alo[BM][LDA];
    __shared__ unsigned short Bhi[BM][LDA];
    __shared__ unsigned short Blo[BM][LDA];

    int tid = threadIdx.x;
    int pBase = blockIdx.x * BM;
    int qBase = blockIdx.y * BM;
    int b = blockIdx.z;

    int srow = tid >> 1;
    int shalf = tid & 1;
    float ia = inv2[b * N_ + qBase + srow];
    float ib = inv1[b * N_ + pBase + srow];
    const float* Abase = f2 + ((size_t)(b * N_ + qBase) + srow) * D_ + shalf * 16;
    const float* Bbase = f1 + ((size_t)(b * N_ + pBase) + srow) * D_ + shalf * 16;

    int lane = tid & 63;
    int wv = tid >> 6;
    int wq = (wv >> 1) * 64;
    int wp = (wv & 1) * 64;
    int fr = lane & 15;
    int kg = lane >> 4;

    f32x4 acc[4][4] = {};

    for (int kb = 0; kb < D_; kb += BK) {
        __syncthreads();
        float4 a0 = *(const float4*)(Abase + kb + 0);
        float4 a1 = *(const float4*)(Abase + kb + 4);
        float4 a2 = *(const float4*)(Abase + kb + 8);
        float4 a3 = *(const float4*)(Abase + kb + 12);
        float4 b0 = *(const float4*)(Bbase + kb + 0);
        float4 b1 = *(const float4*)(Bbase + kb + 4);
        float4 b2 = *(const float4*)(Bbase + kb + 8);
        float4 b3 = *(const float4*)(Bbase + kb + 12);
        uint2 h0, l0, h1, l1, h2, l2, h3, l3;
        split4(a0, ia, h0, l0); split4(a1, ia, h1, l1);
        split4(a2, ia, h2, l2); split4(a3, ia, h3, l3);
        *(uint4*)&Ahi[srow][shalf * 16]     = uint4{h0.x, h0.y, h1.x, h1.y};
        *(uint4*)&Ahi[srow][shalf * 16 + 8] = uint4{h2.x, h2.y, h3.x, h3.y};
        *(uint4*)&Alo[srow][shalf * 16]     = uint4{l0.x, l0.y, l1.x, l1.y};
        *(uint4*)&Alo[srow][shalf * 16 + 8] = uint4{l2.x, l2.y, l3.x, l3.y};
        split4(b0, ib, h0, l0); split4(b1, ib, h1, l1);
        split4(b2, ib, h2, l2); split4(b3, ib, h3, l3);
        *(uint4*)&Bhi[srow][shalf * 16]     = uint4{h0.x, h0.y, h1.x, h1.y};
        *(uint4*)&Bhi[srow][shalf * 16 + 8] = uint4{h2.x, h2.y, h3.x, h3.y};
        *(uint4*)&Blo[srow][shalf * 16]     = uint4{l0.x, l0.y, l1.x, l1.y};
        *(uint4*)&Blo[srow][shalf * 16 + 8] = uint4{l2.x, l2.y, l3.x, l3.y};
        __syncthreads();

        bf16x8 ah[4], al[4], bh[4], bl[4];
#pragma unroll
        for (int t = 0; t < 4; t++) {
            ah[t] = *(const bf16x8*)&Ahi[wq + t * 16 + fr][kg * 8];
            al[t] = *(const bf16x8*)&Alo[wq + t * 16 + fr][kg * 8];
            bh[t] = *(const bf16x8*)&Bhi[wp + t * 16 + fr][kg * 8];
            bl[t] = *(const bf16x8*)&Blo[wp + t * 16 + fr][kg * 8];
        }
#pragma unroll
        for (int qt = 0; qt < 4; qt++) {
#pragma unroll
            for (int pt = 0; pt < 4; pt++) {
                acc[qt][pt] = __builtin_amdgcn_mfma_f32_16x16x32_bf16(
                    ah[qt], bh[pt], acc[qt][pt], 0, 0, 0);
                acc[qt][pt] = __builtin_amdgcn_mfma_f32_16x16x32_bf16(
                    ah[qt], bl[pt], acc[qt][pt], 0, 0, 0);
                acc[qt][pt] = __builtin_amdgcn_mfma_f32_16x16x32_bf16(
                    al[qt], bh[pt], acc[qt][pt], 0, 0, 0);
            }
        }
    }

    // ---------------- epilogue: coord term + MLP + store -------------------
    float px[4], py[4], pz[4], pn2[4];
    int pg[4];
#pragma unroll
    for (int pt = 0; pt < 4; pt++) {
        int p = pBase + wp + pt * 16 + fr;
        pg[pt] = p;
        const float* pp = pc + ((size_t)(b * N_ + p)) * 3;
        px[pt] = pp[0]; py[pt] = pp[1]; pz[pt] = pp[2];
        pn2[pt] = px[pt] * px[pt] + py[pt] * py[pt] + pz[pt] * pz[pt];
    }
#pragma unroll
    for (int qt = 0; qt < 4; qt++) {
        float qx[4], qy[4], qz[4], qq2[4];
        int q0 = qBase + wq + qt * 16 + kg * 4;
#pragma unroll
        for (int r = 0; r < 4; r++) {
            const float* qp = qc + ((size_t)(b * N_ + q0 + r)) * 3;
            qx[r] = qp[0]; qy[r] = qp[1]; qz[r] = qp[2];
            qq2[r] = qx[r] * qx[r] + qy[r] * qy[r] + qz[r] * qz[r];
        }
#pragma unroll
        for (int pt = 0; pt < 4; pt++) {
            f32x4 c = acc[qt][pt];
#pragma unroll
            for (int r = 0; r < 4; r++) {
                float w1v = c[r];
                float d2 = qq2[r] + pn2[pt]
                         - 2.f * (qx[r] * px[pt] + qy[r] * py[pt] + qz[r] * pz[pt]);
                float w2v = -fmaxf(d2, 0.f);
                float out = pb2[0];
#pragma unroll
                for (int h = 0; h < H_; h++) {
                    float t = pW1[2 * h] * w1v + pW1[2 * h + 1] * w2v + pb1[h];
                    out += pW2[h] * fmaxf(t, 0.f);
                }
                w_out[((size_t)(b * N_ + q0 + r)) * N_ + pg[pt]] = out;
            }
        }
    }
}

// ---------------------------------------------------------------------------
// Kernel 3: approx top-32 candidates -> exact fp64 rescore (parallel: 8
// groups of 8 lanes rescore 8 candidates per round, 4 rounds) -> exact top-8
// + softmax + gather + pool. One wave per (b,q) row, 4 rows per block.
// ---------------------------------------------------------------------------
__global__ __launch_bounds__(256)
void topk_kernel(const float* __restrict__ w, const float* __restrict__ f1,
                 const float* __restrict__ f2,
                 const float* __restrict__ pc, const float* __restrict__ qc,
                 const float* __restrict__ pW1, const float* __restrict__ pb1,
                 const float* __restrict__ pW2, const float* __restrict__ pb2,
                 float* __restrict__ f_out, float* __restrict__ idx_out) {
    __shared__ int s_cand[4][CAND];

    int tid  = threadIdx.x;
    int wix  = tid >> 6;
    int lane = tid & 63;
    int row  = blockIdx.x * 4 + wix;          // grid is exact: row < B_*N_
    int b    = row >> 11;
    const float* wrow = w + (size_t)row * N_;

    // ---- phase 1: per-lane sorted top-8 scan of approx scores ----
    float tv[K_];
    int   ti[K_];
#pragma unroll
    for (int s = 0; s < K_; s++) { tv[s] = -INFINITY; ti[s] = 0x7fffffff; }
    for (int j = 0; j < N_ / 256; j++) {
        float4 v4 = *(const float4*)(wrow + lane * 4 + j * 256);
        float vv[4] = {v4.x, v4.y, v4.z, v4.w};
#pragma unroll
        for (int c = 0; c < 4; c++) {
            float v = vv[c];
            if (v > tv[K_ - 1]) {
                int idx = lane * 4 + j * 256 + c;
                tv[K_ - 1] = v; ti[K_ - 1] = idx;
#pragma unroll
                for (int s = K_ - 1; s > 0; s--) {
                    if (tv[s] > tv[s - 1]) {
                        float tf = tv[s]; tv[s] = tv[s - 1]; tv[s - 1] = tf;
                        int tn = ti[s]; ti[s] = ti[s - 1]; ti[s - 1] = tn;
                    }
                }
            }
        }
    }

    // ---- phase 2: pop 32 wave-wide candidates (approx order) -> LDS ----
#pragma unroll
    for (int r = 0; r < CAND; r++) {
        float bv = tv[0];
        int   bi = ti[0];
#pragma unroll
        for (int off = 1; off < 64; off <<= 1) {
            float ov = __shfl_xor(bv, off, 64);
            int   oi = __shfl_xor(bi, off, 64);
            if (ov > bv || (ov == bv && oi < bi)) { bv = ov; bi = oi; }
        }
        if (lane == 0) s_cand[wix][r] = bi;
        if (ti[0] == bi) {
#pragma unroll
            for (int s = 0; s < K_ - 1; s++) { tv[s] = tv[s + 1]; ti[s] = ti[s + 1]; }
            tv[K_ - 1] = -INFINITY; ti[K_ - 1] = 0x7fffffff;
        }
    }
    __syncthreads();

    // ---- phase 3: parallel exact fp64 rescore ----
    // lane = 8*group + slice; round r: group g rescopes cand[8r+g];
    // each lane covers 32 contiguous elements (slice), 3-step group butterfly.
    int sl = lane & 7;
    int gr = lane >> 3;
    const float* f2r = f2 + (size_t)row * D_ + sl * 32;
    float4 a4[8];
#pragma unroll
    for (int t = 0; t < 8; t++) a4[t] = *(const float4*)(f2r + t * 4);

    double daa = 0.0;
#pragma unroll
    for (int t = 0; t < 8; t++) {
        daa += (double)a4[t].x * (double)a4[t].x;
        daa += (double)a4[t].y * (double)a4[t].y;
        daa += (double)a4[t].z * (double)a4[t].z;
        daa += (double)a4[t].w * (double)a4[t].w;
    }
#pragma unroll
    for (int off = 1; off < 8; off <<= 1) daa += __shfl_xor(daa, off, 64);
    double inv_a = 1.0 / (sqrt(daa) + 1e-8);

    double mydab = 0.0, mydbb = 0.0;
    int myci = 0x7fffffff;
#pragma unroll
    for (int r = 0; r < 4; r++) {
        int cj = s_cand[wix][8 * r + gr];
        const float* f1r = f1 + ((size_t)(b * N_ + cj)) * D_ + sl * 32;
        double sA = 0.0, sB = 0.0;
#pragma unroll
        for (int t = 0; t < 8; t++) {
            float4 b4 = *(const float4*)(f1r + t * 4);
            double b0 = b4.x, b1 = b4.y, b2 = b4.z, b3 = b4.w;
            sA += (double)a4[t].x * b0; sB += b0 * b0;
            sA += (double)a4[t].y * b1; sB += b1 * b1;
            sA += (double)a4[t].z * b2; sB += b2 * b2;
            sA += (double)a4[t].w * b3; sB += b3 * b3;
        }
#pragma unroll
        for (int off = 1; off < 8; off <<= 1) {
            sA += __shfl_xor(sA, off, 64);
            sB += __shfl_xor(sB, off, 64);
        }
        if (sl == r) { mydab = sA; mydbb = sB; myci = cj; }
    }

    double ex = -INFINITY;
    int    ei = 0x7fffffff;
    if (sl < 4) {
        ei = myci;
        double w1d = mydab * inv_a * (1.0 / (sqrt(mydbb) + 1e-8));
        const float* qp = qc + (size_t)row * 3;
        double qx = qp[0], qy = qp[1], qz = qp[2];
        const float* pp = pc + ((size_t)(b * N_ + myci)) * 3;
        double px = pp[0], py = pp[1], pz = pp[2];
        double d2 = (qx * qx + qy * qy + qz * qz) + (px * px + py * py + pz * pz)
                  - 2.0 * (qx * px + qy * py + qz * pz);
        double w2d = -fmax(d2, 0.0);
        double out = (double)pb2[0];
#pragma unroll
        for (int h = 0; h < H_; h++) {
            double t = (double)pW1[2 * h] * w1d + (double)pW1[2 * h + 1] * w2d
                     + (double)pb1[h];
            out += (double)pW2[h] * fmax(t, 0.0);
        }
        ex = out;
    }

    // ---- phase 4: exact top-8 over 32 scorer lanes (desc, smaller idx tie) ----
    double outv[K_];
    int    outi[K_];
#pragma unroll
    for (int r = 0; r < K_; r++) {
        double bv = ex;
        int    bi = ei;
#pragma unroll
        for (int off = 1; off < 64; off <<= 1) {
            double ov = __shfl_xor(bv, off, 64);
            int    oi = __shfl_xor(bi, off, 64);
            if (ov > bv || (ov == bv && oi < bi)) { bv = ov; bi = oi; }
        }
        outv[r] = bv; outi[r] = bi;
        if (ei == bi) ex = -INFINITY;   // owning lane retires its candidate
    }

    // ---- phase 5: softmax + gather + pool + write ----
    float m = (float)outv[0];
    float e[K_], s = 0.f;
#pragma unroll
    for (int r = 0; r < K_; r++) { e[r] = expf((float)outv[r] - m); s += e[r]; }
    float inv_s = 1.f / s;

    const float* f1b = f1 + ((size_t)b * N_) * D_;
    size_t obase = (size_t)row * (2 * D_);
#pragma unroll
    for (int jd = 0; jd < D_ / 64; jd++) {
        int d = lane + 64 * jd;
        float accv = 0.f, mx = -INFINITY;
#pragma unroll
        for (int r = 0; r < K_; r++) {
            float x = f1b[(size_t)outi[r] * D_ + d];
            accv += (e[r] * inv_s) * x;
            mx = fmaxf(mx, x);
        }
        f_out[obase + d]      = accv;
        f_out[obase + D_ + d] = mx;
    }
    if (lane == 0) {
#pragma unroll
        for (int r = 0; r < K_; r++) idx_out[(size_t)row * K_ + r] = (float)outi[r];
    }
}

// ---------------------------------------------------------------------------
extern "C" void kernel_launch(void* const* d_in, const int* in_sizes, int n_in,
                              void* d_out, int out_size, void* d_ws, size_t ws_size,
                              hipStream_t stream) {
    const float* f1 = (const float*)d_in[0];
    const float* f2 = (const float*)d_in[1];
    const float* pc = (const float*)d_in[2];
    const float* qc = (const float*)d_in[3];
    const float* W1 = (const float*)d_in[4];
    const float* b1 = (const float*)d_in[5];
    const float* W2 = (const float*)d_in[6];
    const float* b2 = (const float*)d_in[7];

    float* out     = (float*)d_out;
    float* f_out   = out;                                   // [B,N,2D]
    float* idx_out = f_out + (size_t)B_ * N_ * 2 * D_;      // [B,N,K] as float
    float* w_out   = idx_out + (size_t)B_ * N_ * K_;        // [B,N,N]

    float* inv1 = (float*)d_ws;        // [B*N]
    float* inv2 = inv1 + B_ * N_;      // [B*N]

    norm_kernel<<<(2 * B_ * N_) / 4, 256, 0, stream>>>(f1, f2, inv1, inv2);

    dim3 g2(N_ / BM, N_ / BM, B_);
    gemm_mlp_kernel<<<g2, 256, 0, stream>>>(f1, f2, pc, qc, inv1, inv2,
                                            W1, b1, W2, b2, w_out);

    topk_kernel<<<(B_ * N_) / 4, 256, 0, stream>>>(w_out, f1, f2, pc, qc,
                                                   W1, b1, W2, b2,
                                                   f_out, idx_out);
}